// Round 7
// baseline (813.914 us; speedup 1.0000x reference)
//
#include <hip/hip_runtime.h>
#include <cmath>

// INGP hashgrid encode — one-pass phase-rotation design.
//   1024 co-resident blocks (4/CU), each owns 512 consecutive points and
//   sweeps levels 0..15 in lockstep: at any instant all XCDs gather from the
//   SAME 4MiB table -> it pins in every L2 (R6 evidence: gather is L2
//   line-request bound; this balances requests perfectly at 5.5M/XCD vs
//   6.2M max under XCD-level pinning). Results for all 16 levels accumulate
//   in registers -> LDS shuffle -> fully coalesced 128B-row stores. No ws,
//   no transpose kernel (was ~112us), no cross-XCD output lines (R5 lesson).

constexpr int LVLS = 16;
constexpr unsigned TBL = 1u << 19;
constexpr unsigned TMASK = TBL - 1u;
constexpr unsigned P1 = 2654435761u;
constexpr unsigned P2 = 805459861u;

typedef float vf4 __attribute__((ext_vector_type(4)));

struct ResArr { float r[LVLS]; };

__global__ __launch_bounds__(256, 4) void ingp_onepass(
    const float* __restrict__ pts,
    const float* __restrict__ tables,
    float* __restrict__ out,      // [N][LVLS*2] floats
    ResArr ra, int npts)
{
    int t = threadIdx.x;
    int base = blockIdx.x * 512;

    // Load this thread's 2 points once (nt: streamed, don't pollute L2).
    float X[2], Y[2], Z[2];
    bool valid[2];
    int pidx[2] = { base + t, base + t + 256 };
    #pragma unroll
    for (int s = 0; s < 2; ++s) {
        valid[s] = pidx[s] < npts;
        int pp = valid[s] ? pidx[s] : 0;
        float px = __builtin_nontemporal_load(pts + pp * 3 + 0);
        float py = __builtin_nontemporal_load(pts + pp * 3 + 1);
        float pz = __builtin_nontemporal_load(pts + pp * 3 + 2);
        X[s] = (px + 1.0f) * 0.5f;
        Y[s] = (py + 1.0f) * 0.5f;
        Z[s] = (pz + 1.0f) * 0.5f;
    }

    float acc[2][LVLS][2];   // [point][level][feature] in registers

    #pragma unroll
    for (int l = 0; l < LVLS; ++l) {
        float r = ra.r[l];
        const float2* __restrict__ tab = (const float2*)tables + (size_t)l * TBL;

        #pragma unroll
        for (int s = 0; s < 2; ++s) {
            float posx = X[s] * r, posy = Y[s] * r, posz = Z[s] * r;
            float fx = floorf(posx), fy = floorf(posy), fz = floorf(posz);
            float wx = posx - fx, wy = posy - fy, wz = posz - fz;
            unsigned ix = (unsigned)fx, iy = (unsigned)fy, iz = (unsigned)fz;
            unsigned hx0 = ix,      hx1 = ix + 1u;
            unsigned hy0 = iy * P1, hy1 = hy0 + P1;
            unsigned hz0 = iz * P2, hz1 = hz0 + P2;

            unsigned hyz[4];
            hyz[0] = hy0 ^ hz0;
            hyz[1] = hy0 ^ hz1;
            hyz[2] = hy1 ^ hz0;
            hyz[3] = hy1 ^ hz1;

            // v[i*4+yz] = corner (i,j,k); x-pairs share an aligned float4
            // when ix is even (R6: 8 -> 6 avg line-requests).
            float2 v[8];
            if ((ix & 1u) == 0u) {
                #pragma unroll
                for (int yz = 0; yz < 4; ++yz) {
                    unsigned b0 = (hx0 ^ hyz[yz]) & TMASK;
                    const vf4* lp = (const vf4*)(tab + (b0 & ~1u));
                    vf4 qd = *lp;
                    float2 lo = make_float2(qd.x, qd.y);
                    float2 hi = make_float2(qd.z, qd.w);
                    bool odd = (b0 & 1u) != 0u;
                    v[yz]     = odd ? hi : lo;
                    v[4 + yz] = odd ? lo : hi;
                }
            } else {
                #pragma unroll
                for (int yz = 0; yz < 4; ++yz) {
                    unsigned b0 = (hx0 ^ hyz[yz]) & TMASK;
                    unsigned b1 = (hx1 ^ hyz[yz]) & TMASK;
                    v[yz]     = tab[b0];
                    v[4 + yz] = tab[b1];
                }
            }

            float ox = 1.0f - wx, oy = 1.0f - wy, oz = 1.0f - wz;
            float w[8];
            w[0] = (ox * oy) * oz;
            w[1] = (ox * oy) * wz;
            w[2] = (ox * wy) * oz;
            w[3] = (ox * wy) * wz;
            w[4] = (wx * oy) * oz;
            w[5] = (wx * oy) * wz;
            w[6] = (wx * wy) * oz;
            w[7] = (wx * wy) * wz;

            float f0 = w[0] * v[0].x;
            float f1 = w[0] * v[0].y;
            #pragma unroll
            for (int c = 1; c < 8; ++c) {
                f0 += w[c] * v[c].x;
                f1 += w[c] * v[c].y;
            }
            acc[s][l][0] = f0;
            acc[s][l][1] = f1;
        }
    }

    // Epilogue: LDS shuffle (256-pt half-tiles) -> coalesced 16B stores of
    // complete output rows. Row pad 17 float2: write phase conflict-free.
    __shared__ float2 lds[256][17];
    int j = t & 7;     // which float4 of the 128B row
    int pr = t >> 3;   // point-in-tile, advances by 32

    #pragma unroll
    for (int h = 0; h < 2; ++h) {
        if (h) __syncthreads();   // protect LDS reuse
        #pragma unroll
        for (int l = 0; l < LVLS; ++l)
            lds[t][l] = make_float2(acc[h][l][0], acc[h][l][1]);
        __syncthreads();

        #pragma unroll
        for (int it = 0; it < 8; ++it) {
            int pt = pr + it * 32;
            int gp = base + h * 256 + pt;
            if (gp < npts) {
                float2 u = lds[pt][2 * j];
                float2 w2 = lds[pt][2 * j + 1];
                vf4 o; o.x = u.x; o.y = u.y; o.z = w2.x; o.w = w2.y;
                __builtin_nontemporal_store(o, (vf4*)(out + (size_t)gp * 32 + j * 4));
            }
        }
    }
}

extern "C" void kernel_launch(void* const* d_in, const int* in_sizes, int n_in,
                              void* d_out, int out_size, void* d_ws, size_t ws_size,
                              hipStream_t stream) {
    const float* pts    = (const float*)d_in[0];
    const float* tables = (const float*)d_in[1];
    int npts = in_sizes[0] / 3;

    // numpy-bitwise RES: GROWTH = exp((log(2048)-log(16))/15); floor(16*G**l)
    ResArr ra;
    double growth = exp((log(2048.0) - log(16.0)) / 15.0);
    for (int l = 0; l < LVLS; ++l)
        ra.r[l] = (float)floor(16.0 * pow(growth, (double)l));

    int grid = (npts + 511) / 512;
    hipLaunchKernelGGL(ingp_onepass, dim3(grid), dim3(256), 0, stream,
                       pts, tables, (float*)d_out, ra, npts);
}